// Round 16
// baseline (200.811 us; speedup 1.0000x reference)
//
#include <hip/hip_runtime.h>
#include <math.h>

#define POFF 128

// ---------------------------------------------------------------------------
// Phase 1: natural cubic spline coefficients via PCR (validated R15).
// ---------------------------------------------------------------------------
__global__ void __launch_bounds__(256)
spline_setup(const float* __restrict__ delay_in,
             const float* __restrict__ raw,
             double* __restrict__ coef,
             int* __restrict__ minz,
             int nf) {
    __shared__ double xch[3 * 256];
    __shared__ double Aa[2][512], Ab[2][512], Ac[2][512];
    __shared__ double Ad0[2][512], Ad1[2][512], Ad2[2][512];

    const int tid = threadIdx.x;
    if (tid == 0) *minz = 0x7fffffff;

    #pragma unroll
    for (int b = 0; b < 2; ++b)
        for (int i = tid; i < 512; i += 256) {
            Aa[b][i] = 0.0; Ab[b][i] = 1.0; Ac[b][i] = 0.0;
            Ad0[b][i] = 0.0; Ad1[b][i] = 0.0; Ad2[b][i] = 0.0;
        }

    if (tid < nf) {
        double s0 = 1.0 / (1.0 + exp(-(double)raw[2 * tid + 0]));
        double s1 = 1.0 / (1.0 + exp(-(double)raw[2 * tid + 1]));
        double ss = s0 + s1;
        xch[0 * 256 + tid] = (double)delay_in[tid];
        xch[1 * 256 + tid] = s0 / ss;
        xch[2 * 256 + tid] = s1 / ss;
    }
    __syncthreads();

    if (tid < nf) {
        int i = tid;
        double hinv = (double)(nf - 1);
        Aa[0][POFF + i] = (i > 0) ? 1.0 : 0.0;
        Ac[0][POFF + i] = (i < nf - 1) ? 1.0 : 0.0;
        Ab[0][POFF + i] = (i == 0 || i == nf - 1) ? 2.0 : 4.0;
        #pragma unroll
        for (int ch = 0; ch < 3; ++ch) {
            const double* x = xch + ch * 256;
            double r = 0.0;
            if (i < nf - 1) r += 3.0 * hinv * (x[i + 1] - x[i]);
            if (i > 0)      r += 3.0 * hinv * (x[i] - x[i - 1]);
            if (ch == 0) Ad0[0][POFF + i] = r;
            else if (ch == 1) Ad1[0][POFF + i] = r;
            else Ad2[0][POFF + i] = r;
        }
    }
    __syncthreads();

    int cur = 0;
    for (int s = 1; s < nf; s <<= 1) {
        int nxt = cur ^ 1;
        int ic = POFF + tid, im = ic - s, ip = ic + s;
        double ai = Aa[cur][ic], bi = Ab[cur][ic], ci = Ac[cur][ic];
        double alpha = -ai / Ab[cur][im];
        double gamma = -ci / Ab[cur][ip];
        double na = alpha * Aa[cur][im];
        double nc = gamma * Ac[cur][ip];
        double nb = bi + alpha * Ac[cur][im] + gamma * Aa[cur][ip];
        double n0 = Ad0[cur][ic] + alpha * Ad0[cur][im] + gamma * Ad0[cur][ip];
        double n1 = Ad1[cur][ic] + alpha * Ad1[cur][im] + gamma * Ad1[cur][ip];
        double n2 = Ad2[cur][ic] + alpha * Ad2[cur][im] + gamma * Ad2[cur][ip];
        Aa[nxt][ic] = na; Ab[nxt][ic] = nb; Ac[nxt][ic] = nc;
        Ad0[nxt][ic] = n0; Ad1[nxt][ic] = n1; Ad2[nxt][ic] = n2;
        cur = nxt;
        __syncthreads();
    }

    int nint = nf - 1;
    double hinv = (double)(nf - 1);
    if (tid < nint) {
        int i = tid;
        double rbI = 1.0 / Ab[cur][POFF + i], rbI1 = 1.0 / Ab[cur][POFF + i + 1];
        #pragma unroll
        for (int ch = 0; ch < 3; ++ch) {
            double ki, ki1;
            if (ch == 0) { ki = Ad0[cur][POFF + i] * rbI; ki1 = Ad0[cur][POFF + i + 1] * rbI1; }
            else if (ch == 1) { ki = Ad1[cur][POFF + i] * rbI; ki1 = Ad1[cur][POFF + i + 1] * rbI1; }
            else { ki = Ad2[cur][POFF + i] * rbI; ki1 = Ad2[cur][POFF + i + 1] * rbI1; }
            const double* x = xch + ch * 256;
            double dx3 = 3.0 * (x[i + 1] - x[i]);
            double two_c   = (2.0 * dx3 * hinv - 4.0 * ki - 2.0 * ki1) * hinv;
            double three_d = (-2.0 * dx3 * hinv + 3.0 * (ki + ki1)) * hinv * hinv;
            double* C = coef + (size_t)(ch * nint + i) * 4;
            C[0] = x[i];
            C[1] = ki;
            C[2] = 0.5 * two_c;
            C[3] = three_d * (1.0 / 3.0);
        }
    }
}

// ---------------------------------------------------------------------------
// Spline eval at sample j (f64). Returns z and taps A1,A2,A3.
// ---------------------------------------------------------------------------
__device__ __forceinline__ void eval_at(const double* __restrict__ coef,
                                        int nf, int n, int j,
                                        int& z, double& A1, double& A2, double& A3) {
    double u = (double)j / (double)(n - 1);
    double nfm1 = (double)(nf - 1);
    int idx = (int)(u * nfm1);
    if (idx > nf - 2) idx = nf - 2;
    if (idx < 0) idx = 0;
    double tknot = (double)idx / nfm1;
    if (u < tknot && idx > 0) {
        idx--; tknot = (double)idx / nfm1;
    } else {
        double tnext = (double)(idx + 1) / nfm1;
        if (u >= tnext && idx < nf - 2) { idx++; tknot = tnext; }
    }
    double f = u - tknot;
    int nint = nf - 1;
    const double* C0 = coef + (size_t)(0 * nint + idx) * 4;
    const double* C1 = coef + (size_t)(1 * nint + idx) * 4;
    const double* C2 = coef + (size_t)(2 * nint + idx) * 4;
    double dly = C0[0] + f * (C0[1] + f * (C0[2] + f * C0[3]));
    double b1d = C1[0] + f * (C1[1] + f * (C1[2] + f * C1[3]));
    double b2d = C2[0] + f * (C2[1] + f * (C2[2] + f * C2[3]));
    double zf = floor(dly);
    z = (int)zf;
    double alfa = dly - zf;
    A1 = b1d * (1.0 - alfa);
    A2 = b1d * alfa + b2d * (1.0 - alfa);
    A3 = b2d * alfa;
}

// ---------------------------------------------------------------------------
// Phase 2: per-sample eval + TAP EXPANSION (D=128 chunks).
// Layout per chunk c (256 float4): [row0 q:64][v0:64][v1:64][v2:64].
// row0 (offset<64, never in-chunk): q = {A1,A2,A3, s3=(j-z-3)&2047}.
// row1: up to 3 contiguous-triple tap groups. Taps with z+i <= offset are
// in-chunk -> substituted once (their own taps reach >= 2*(minz+1) >= 128
// back, escaping the chunk; valid iff minz >= 63 = scan's guard).
// e3=>e2=>e1 so groups = residual (if k<3) + k expansions <= 3.
// const = x[j] + sum(expanded Ai*x[j-di]) -> scan needs no excitation for row1.
// v0={G0.c0,c1,c2, const}; v1={G1.c, pk(G0.b|G1.b<<11)}; v2={G2.c, G2.b}.
// buf[Gb+0] pairs c0 (oldest tap), +2 pairs c2 (newest).
// ---------------------------------------------------------------------------
__global__ void eval_kernel(const double* __restrict__ coef,
                            const float* __restrict__ exc,
                            float4* __restrict__ gx,
                            int* __restrict__ minz,
                            int n, int nChTot, int nf, int burst) {
    int j = blockIdx.x * blockDim.x + threadIdx.x;
    if (j >= (nChTot << 7)) return;
    int c = j >> 7, off = j & 127;
    float4* base = gx + ((size_t)c << 8);
    if (j >= n) {
        float4 zf4 = make_float4(0.f, 0.f, 0.f, 0.f);
        if (off < 64) base[off] = zf4;
        else {
            int o = off - 64;
            base[64 + o] = zf4; base[128 + o] = zf4; base[192 + o] = zf4;
        }
        return;
    }
    int z; double A1, A2, A3;
    eval_at(coef, nf, n, j, z, A1, A2, A3);

    int wmin = z;
    #pragma unroll
    for (int o = 32; o > 0; o >>= 1) wmin = min(wmin, __shfl_down(wmin, o, 64));
    if ((threadIdx.x & 63) == 0) atomicMin(minz, wmin);

    if (off < 64) {
        unsigned s3 = (unsigned)((j - z - 3) & 2047);
        base[off] = make_float4((float)A1, (float)A2, (float)A3, __uint_as_float(s3));
        return;
    }
    int o = off - 64;
    bool e1 = (z + 1) <= off, e2 = (z + 2) <= off, e3 = (z + 3) <= off;
    double cst = (j < burst) ? (double)exc[j] : 0.0;

    double x1c0 = 0, x1c1 = 0, x1c2 = 0; unsigned x1b = 0;
    double x2c0 = 0, x2c1 = 0, x2c2 = 0; unsigned x2b = 0;
    double x3c0 = 0, x3c1 = 0, x3c2 = 0; unsigned x3b = 0;
    if (e1) {
        int t2 = j - z - 1; int z2; double B1, B2, B3;
        eval_at(coef, nf, n, t2, z2, B1, B2, B3);
        cst += A1 * ((t2 < burst) ? (double)exc[t2] : 0.0);
        x1b = (unsigned)((t2 - z2 - 3) & 2047);
        x1c0 = A1 * B3; x1c1 = A1 * B2; x1c2 = A1 * B1;
    }
    if (e2) {
        int t2 = j - z - 2; int z2; double B1, B2, B3;
        eval_at(coef, nf, n, t2, z2, B1, B2, B3);
        cst += A2 * ((t2 < burst) ? (double)exc[t2] : 0.0);
        x2b = (unsigned)((t2 - z2 - 3) & 2047);
        x2c0 = A2 * B3; x2c1 = A2 * B2; x2c2 = A2 * B1;
    }
    if (e3) {
        int t2 = j - z - 3; int z2; double B1, B2, B3;
        eval_at(coef, nf, n, t2, z2, B1, B2, B3);
        cst += A3 * ((t2 < burst) ? (double)exc[t2] : 0.0);
        x3b = (unsigned)((t2 - z2 - 3) & 2047);
        x3c0 = A3 * B3; x3c1 = A3 * B2; x3c2 = A3 * B1;
    }
    double rc0 = e3 ? 0.0 : A3, rc1 = e2 ? 0.0 : A2, rc2 = e1 ? 0.0 : A1;
    unsigned rb = (unsigned)((j - z - 3) & 2047);
    // pack: k==3 -> {exp1,exp2,exp3}; else {residual, exp1, exp2}
    double g0c0 = e3 ? x1c0 : rc0, g0c1 = e3 ? x1c1 : rc1, g0c2 = e3 ? x1c2 : rc2;
    unsigned g0b = e3 ? x1b : rb;
    double g1c0 = e3 ? x2c0 : x1c0, g1c1 = e3 ? x2c1 : x1c1, g1c2 = e3 ? x2c2 : x1c2;
    unsigned g1b = e3 ? x2b : x1b;
    double g2c0 = e3 ? x3c0 : x2c0, g2c1 = e3 ? x3c1 : x2c1, g2c2 = e3 ? x3c2 : x2c2;
    unsigned g2b = e3 ? x3b : x2b;

    unsigned pkA = g0b | (g1b << 11);
    base[64 + o]  = make_float4((float)g0c0, (float)g0c1, (float)g0c2, (float)cst);
    base[128 + o] = make_float4((float)g1c0, (float)g1c1, (float)g1c2, __uint_as_float(pkA));
    base[192 + o] = make_float4((float)g2c0, (float)g2c1, (float)g2c2, __uint_as_float(g2b));
}

// ---------------------------------------------------------------------------
// Phase 3: producer/consumer, D=128 chunks (1024 serial steps vs 2048 in
// R13). Group = 8 chunks = 1024 samples; ring 3-deep (96 KB). All offsets
// compile-time. Rows 0 and 1 of a chunk are independent (expansion ensures
// all reads target < chunk base) -> one LDS round-trip per 128 samples.
// Producer per group: exactly 16 y-offload stores + 32 global_load_lds
// (group g+2 -> slot (g+2)%3) + counted vmcnt(48); loads stay in flight
// across the raw s_barrier (R11/R13-validated).
// ---------------------------------------------------------------------------
__global__ void __launch_bounds__(128, 1)
scan_kernel(const float4* __restrict__ gx,
            const int* __restrict__ minz,
            const float* __restrict__ exc,
            float* __restrict__ y,
            float* __restrict__ sink,
            int n, int burst) {
    __shared__ float buf[2052];            // 2048 circular + 2 shadow + pad
    __shared__ float excl[2048];
    __shared__ float4 ring[3 * 2048];      // 3 slots x 8 chunks x 256 f4 = 96 KB

    const int tid = threadIdx.x;
    for (int i = tid; i < 2052; i += 128) buf[i] = 0.0f;
    for (int i = tid; i < 2048; i += 128) excl[i] = (i < burst) ? exc[i] : 0.0f;

    int mz = __builtin_amdgcn_readfirstlane(*minz);
    const int nFull = n >> 10;

#define GLL(gsrc, ldst)                                                       \
    __builtin_amdgcn_global_load_lds(                                         \
        (const __attribute__((address_space(1))) void*)(gsrc),                \
        (__attribute__((address_space(3))) void*)(ldst), 16, 0, 0)

    // ---------------- fallback (format-aware; not taken for this data) -----
    if (mz < 63 || (n & 1023) != 0 || nFull < 3) {
        __syncthreads();
        if (tid < 64) {
            int Df = mz + 1;
            if (Df > 64) Df = 64;
            if (Df < 1) Df = 1;
            for (int bs = 0; bs < n; bs += Df) {
                int t = bs + tid;
                bool ok = (tid < Df) && (t < n);
                float yv = 0.0f;
                if (ok) {
                    int cc = t >> 7, of = t & 127;
                    const float4* bp = gx + ((size_t)cc << 8);
                    if (of < 64) {
                        float4 q = bp[of];
                        unsigned u = __float_as_uint(q.w);
                        float xv = (t < burst) ? excl[t & 2047] : 0.0f;
                        yv = fmaf(q.x, buf[u + 2], xv);
                        yv = fmaf(q.y, buf[u + 1], yv);
                        yv = fmaf(q.z, buf[u], yv);
                    } else {
                        int oo = of - 64;
                        float4 v0 = bp[64 + oo], v1 = bp[128 + oo], v2 = bp[192 + oo];
                        unsigned pkA = __float_as_uint(v1.w);
                        unsigned b0 = pkA & 2047u, b1 = (pkA >> 11) & 2047u;
                        unsigned b2 = __float_as_uint(v2.w);
                        yv = v0.w;
                        yv += v0.x * buf[b0] + v0.y * buf[b0 + 1] + v0.z * buf[b0 + 2];
                        yv += v1.x * buf[b1] + v1.y * buf[b1 + 1] + v1.z * buf[b1 + 2];
                        yv += v2.x * buf[b2] + v2.y * buf[b2 + 1] + v2.z * buf[b2 + 2];
                    }
                }
                if (ok) {
                    int w = t & 2047;
                    buf[w] = yv;
                    if (w < 2) buf[2048 + w] = yv;
                    y[t] = yv;
                }
            }
        }
        return;
    }

    // ---------------- prologue: fill ring slots 0,1 (groups 0,1) -----------
    if (tid >= 64) {
        int lane = tid - 64;
        #pragma unroll
        for (int k = 0; k < 32; ++k)
            GLL(gx + (k << 6) + lane, &ring[(k << 6)]);
        #pragma unroll
        for (int k = 0; k < 32; ++k)
            GLL(gx + 2048 + (k << 6) + lane, &ring[2048 + (k << 6)]);
    }
    __syncthreads();   // full drain: groups 0,1 resident; buf/excl visible

    int csel = 0;                      // g % 3
    int psel = 2;                      // (g+2) % 3
    for (int g = 0; g < nFull; ++g) {
        if (tid >= 64) {
            // ---------------- producer ----------------
            int lane = tid - 64;
            int prevw = ((g - 1) & 1) << 10;
            int prev = (g - 1) << 10;
            float vals[16];
            #pragma unroll
            for (int k = 0; k < 16; ++k)
                vals[k] = buf[prevw + (k << 6) + lane];
            #pragma unroll
            for (int k = 0; k < 16; ++k) {
                int offs = (k << 6) + lane;
                float* dst = (g > 0) ? (y + prev + offs) : (sink + offs);
                *dst = vals[k];                    // exactly 16 stores
            }
            const float4* src = gx + ((size_t)(g + 2) << 11);
            float4* dl = ring + psel * 2048;
            #pragma unroll
            for (int k = 0; k < 32; ++k)
                GLL(src + (k << 6) + lane, dl + (k << 6));
            // counted wait: prev group's 48 ops drained (incl. g+1's loads)
            asm volatile("s_waitcnt vmcnt(48)" ::: "memory");
        } else {
            // ---------------- consumer (pure LDS) ----------------
            const float4* Rp = ring + csel * 2048;
            int wb = ((g & 1) << 10) + tid;
            int gb = g << 10;
            bool wx = (gb < burst);                // uniform; first 2 groups
            float4 q  = Rp[tid];
            float4 v0 = Rp[64 + tid];
            float4 v1 = Rp[128 + tid];
            float4 v2 = Rp[192 + tid];
            #pragma unroll
            for (int c = 0; c < 8; ++c) {
                float4 qn, w0n, w1n, w2n;
                if (c < 7) {
                    qn  = Rp[((c + 1) << 8) + tid];
                    w0n = Rp[((c + 1) << 8) + 64 + tid];
                    w1n = Rp[((c + 1) << 8) + 128 + tid];
                    w2n = Rp[((c + 1) << 8) + 192 + tid];
                }
                // row0 (offsets 0-63): R13 body
                unsigned u = __float_as_uint(q.w);
                float a3 = buf[u], a2 = buf[u + 1], a1 = buf[u + 2];
                float x0 = 0.0f;
                if (wx) {
                    int t = gb + (c << 7) + tid;
                    x0 = (t < burst) ? excl[t & 2047] : 0.0f;
                }
                float y0 = fmaf(q.x, a1, x0);
                y0 = fmaf(q.y, a2, y0);
                y0 = fmaf(q.z, a3, y0);
                // row1 (offsets 64-127): 3 tap groups, const includes x
                unsigned pkA = __float_as_uint(v1.w);
                unsigned b0 = pkA & 2047u;
                unsigned b1i = (pkA >> 11) & 2047u;
                unsigned b2i = __float_as_uint(v2.w);
                float h00 = buf[b0],  h01 = buf[b0 + 1],  h02 = buf[b0 + 2];
                float h10 = buf[b1i], h11 = buf[b1i + 1], h12 = buf[b1i + 2];
                float h20 = buf[b2i], h21 = buf[b2i + 1], h22 = buf[b2i + 2];
                float s0 = fmaf(v0.x, h00, fmaf(v0.y, h01, v0.z * h02));
                float s1 = fmaf(v1.x, h10, fmaf(v1.y, h11, v1.z * h12));
                float s2 = fmaf(v2.x, h20, fmaf(v2.y, h21, v2.z * h22));
                float y1v = (v0.w + s0) + (s1 + s2);
                buf[wb + (c << 7)] = y0;
                buf[wb + (c << 7) + 64] = y1v;
                if (c == 0 && (g & 1) == 0 && tid < 2) buf[2048 + tid] = y0;
                q = qn; v0 = w0n; v1 = w1n; v2 = w2n;
            }
        }
        // raw barrier: producer's g+2 loads stay in flight across it
        asm volatile("s_waitcnt lgkmcnt(0)" ::: "memory");
        __builtin_amdgcn_sched_barrier(0);
        __builtin_amdgcn_s_barrier();
        __builtin_amdgcn_sched_barrier(0);
        csel = (csel == 2) ? 0 : csel + 1;
        psel = (psel == 2) ? 0 : psel + 1;
    }

    __syncthreads();   // drain everything before epilogue

    if (tid >= 64) {
        // offload group nFull-1 (final in buf)
        int lane = tid - 64;
        int start = (nFull - 1) << 10;
        #pragma unroll
        for (int k = 0; k < 16; ++k) {
            int t = start + (k << 6) + lane;
            if (t < n) y[t] = buf[t & 2047];
        }
    }
#undef GLL
}

// ---------------------------------------------------------------------------
extern "C" void kernel_launch(void* const* d_in, const int* in_sizes, int n_in,
                              void* d_out, int out_size, void* d_ws, size_t ws_size,
                              hipStream_t stream) {
    const float* delay = (const float*)d_in[0];
    const float* raw   = (const float*)d_in[1];
    const float* exc   = (const float*)d_in[2];
    int nf = in_sizes[0];
    int burst = in_sizes[2];
    if (burst > 2048) burst = 2048;
    int n = out_size;
    int nChTot = ((n + 127) >> 7) + 16;    // +2 groups prefetch overshoot

    char* ws = (char*)d_ws;
    size_t coefBytes = (size_t)3 * (nf - 1) * 4 * sizeof(double);
    size_t off = (coefBytes + 255) & ~(size_t)255;
    double* coef = (double*)ws;
    int* minz = (int*)(ws + off);
    off += 256;
    float* sink = (float*)(ws + off);
    off += 4096;
    float4* gxa = (float4*)(ws + off);     // nChTot * 256 float4

    spline_setup<<<1, 256, 0, stream>>>(delay, raw, coef, minz, nf);
    int nTotS = nChTot << 7;
    eval_kernel<<<(nTotS + 255) / 256, 256, 0, stream>>>(coef, exc, gxa, minz, n, nChTot, nf, burst);
    scan_kernel<<<1, 128, 0, stream>>>(gxa, minz, exc, (float*)d_out, sink, n, burst);
}

// Round 17
// 183.915 us; speedup vs baseline: 1.0919x; 1.0919x over previous
//
#include <hip/hip_runtime.h>
#include <math.h>

#define POFF 128

// ---------------------------------------------------------------------------
// Phase 1: natural cubic spline coefficients via PCR (validated R15).
// Also inits global minz and per-chunk (128-sample) min-z table.
// ---------------------------------------------------------------------------
__global__ void __launch_bounds__(256)
spline_setup(const float* __restrict__ delay_in,
             const float* __restrict__ raw,
             double* __restrict__ coef,
             int* __restrict__ minz,
             int* __restrict__ chunkmin,
             int nChTot, int nf) {
    __shared__ double xch[3 * 256];
    __shared__ double Aa[2][512], Ab[2][512], Ac[2][512];
    __shared__ double Ad0[2][512], Ad1[2][512], Ad2[2][512];

    const int tid = threadIdx.x;
    if (tid == 0) *minz = 0x7fffffff;
    for (int i = tid; i < nChTot; i += 256) chunkmin[i] = 0x7fffffff;

    #pragma unroll
    for (int b = 0; b < 2; ++b)
        for (int i = tid; i < 512; i += 256) {
            Aa[b][i] = 0.0; Ab[b][i] = 1.0; Ac[b][i] = 0.0;
            Ad0[b][i] = 0.0; Ad1[b][i] = 0.0; Ad2[b][i] = 0.0;
        }

    if (tid < nf) {
        double s0 = 1.0 / (1.0 + exp(-(double)raw[2 * tid + 0]));
        double s1 = 1.0 / (1.0 + exp(-(double)raw[2 * tid + 1]));
        double ss = s0 + s1;
        xch[0 * 256 + tid] = (double)delay_in[tid];
        xch[1 * 256 + tid] = s0 / ss;
        xch[2 * 256 + tid] = s1 / ss;
    }
    __syncthreads();

    if (tid < nf) {
        int i = tid;
        double hinv = (double)(nf - 1);
        Aa[0][POFF + i] = (i > 0) ? 1.0 : 0.0;
        Ac[0][POFF + i] = (i < nf - 1) ? 1.0 : 0.0;
        Ab[0][POFF + i] = (i == 0 || i == nf - 1) ? 2.0 : 4.0;
        #pragma unroll
        for (int ch = 0; ch < 3; ++ch) {
            const double* x = xch + ch * 256;
            double r = 0.0;
            if (i < nf - 1) r += 3.0 * hinv * (x[i + 1] - x[i]);
            if (i > 0)      r += 3.0 * hinv * (x[i] - x[i - 1]);
            if (ch == 0) Ad0[0][POFF + i] = r;
            else if (ch == 1) Ad1[0][POFF + i] = r;
            else Ad2[0][POFF + i] = r;
        }
    }
    __syncthreads();

    int cur = 0;
    for (int s = 1; s < nf; s <<= 1) {
        int nxt = cur ^ 1;
        int ic = POFF + tid, im = ic - s, ip = ic + s;
        double ai = Aa[cur][ic], bi = Ab[cur][ic], ci = Ac[cur][ic];
        double alpha = -ai / Ab[cur][im];
        double gamma = -ci / Ab[cur][ip];
        double na = alpha * Aa[cur][im];
        double nc = gamma * Ac[cur][ip];
        double nb = bi + alpha * Ac[cur][im] + gamma * Aa[cur][ip];
        double n0 = Ad0[cur][ic] + alpha * Ad0[cur][im] + gamma * Ad0[cur][ip];
        double n1 = Ad1[cur][ic] + alpha * Ad1[cur][im] + gamma * Ad1[cur][ip];
        double n2 = Ad2[cur][ic] + alpha * Ad2[cur][im] + gamma * Ad2[cur][ip];
        Aa[nxt][ic] = na; Ab[nxt][ic] = nb; Ac[nxt][ic] = nc;
        Ad0[nxt][ic] = n0; Ad1[nxt][ic] = n1; Ad2[nxt][ic] = n2;
        cur = nxt;
        __syncthreads();
    }

    int nint = nf - 1;
    double hinv = (double)(nf - 1);
    if (tid < nint) {
        int i = tid;
        double rbI = 1.0 / Ab[cur][POFF + i], rbI1 = 1.0 / Ab[cur][POFF + i + 1];
        #pragma unroll
        for (int ch = 0; ch < 3; ++ch) {
            double ki, ki1;
            if (ch == 0) { ki = Ad0[cur][POFF + i] * rbI; ki1 = Ad0[cur][POFF + i + 1] * rbI1; }
            else if (ch == 1) { ki = Ad1[cur][POFF + i] * rbI; ki1 = Ad1[cur][POFF + i + 1] * rbI1; }
            else { ki = Ad2[cur][POFF + i] * rbI; ki1 = Ad2[cur][POFF + i + 1] * rbI1; }
            const double* x = xch + ch * 256;
            double dx3 = 3.0 * (x[i + 1] - x[i]);
            double two_c   = (2.0 * dx3 * hinv - 4.0 * ki - 2.0 * ki1) * hinv;
            double three_d = (-2.0 * dx3 * hinv + 3.0 * (ki + ki1)) * hinv * hinv;
            double* C = coef + (size_t)(ch * nint + i) * 4;
            C[0] = x[i];
            C[1] = ki;
            C[2] = 0.5 * two_c;
            C[3] = three_d * (1.0 / 3.0);
        }
    }
}

// ---------------------------------------------------------------------------
// Phase 2: per-sample spline eval -> {g1, g2, g3, s3} one float4 (R15
// format). s3 = (t - z - 3) & 2047. Global min z + per-128-chunk min z via
// one atomic each per wave (waves never straddle a chunk: 64 | 128, blocks
// 256-aligned). Pads [n, nTot) with zeros.
// ---------------------------------------------------------------------------
__global__ void eval_kernel(const double* __restrict__ coef,
                            float4* __restrict__ gx,
                            int* __restrict__ minz,
                            int* __restrict__ chunkmin,
                            int n, int nTot, int nf) {
    int j = blockIdx.x * blockDim.x + threadIdx.x;
    if (j >= nTot) return;
    if (j >= n) { gx[j] = make_float4(0.f, 0.f, 0.f, 0.f); return; }

    double u = (double)j / (double)(n - 1);
    double nfm1 = (double)(nf - 1);
    int idx = (int)(u * nfm1);
    if (idx > nf - 2) idx = nf - 2;
    if (idx < 0) idx = 0;
    double tknot = (double)idx / nfm1;
    if (u < tknot && idx > 0) {
        idx--; tknot = (double)idx / nfm1;
    } else {
        double tnext = (double)(idx + 1) / nfm1;
        if (u >= tnext && idx < nf - 2) { idx++; tknot = tnext; }
    }
    double f = u - tknot;

    int nint = nf - 1;
    const double* C0 = coef + (size_t)(0 * nint + idx) * 4;
    const double* C1 = coef + (size_t)(1 * nint + idx) * 4;
    const double* C2 = coef + (size_t)(2 * nint + idx) * 4;
    double dly = C0[0] + f * (C0[1] + f * (C0[2] + f * C0[3]));
    double b1d = C1[0] + f * (C1[1] + f * (C1[2] + f * C1[3]));
    double b2d = C2[0] + f * (C2[1] + f * (C2[2] + f * C2[3]));

    double zf = floor(dly);
    int z = (int)zf;
    float alfa = (float)(dly - zf);
    float b1 = (float)b1d, b2 = (float)b2d;
    float g1 = b1 * (1.0f - alfa);
    float g2 = b1 * alfa + b2 * (1.0f - alfa);
    float g3 = b2 * alfa;

    int s3 = (j - z - 3) & 2047;
    gx[j] = make_float4(g1, g2, g3, __uint_as_float((unsigned int)s3));

    int wmin = z;
    #pragma unroll
    for (int o = 32; o > 0; o >>= 1) wmin = min(wmin, __shfl_down(wmin, o, 64));
    if ((threadIdx.x & 63) == 0) {
        atomicMin(minz, wmin);
        atomicMin(&chunkmin[j >> 7], wmin);   // chunk-uniform within a wave
    }
}

// ---------------------------------------------------------------------------
// Phase 3: producer/consumer, D=128 chunks with per-chunk FAST/SLOW path.
// FAST (chunk min z >= 127): all 128 samples' taps reach < chunk base ->
// rows 0,1 independent -> ONE LDS round-trip per 128 samples (R13's
// per-sample cost, half the steps). SLOW (z dips < 127, ~20% of chunks):
// rows sequential (R13 rate). Branch is wave-uniform scalar (readfirstlane
// of flags int4-loaded at group start, latency hidden under chunk 0).
// Group = 8 chunks = 1024 samples. Producer/ring/epilogue = R13 verbatim
// (16 y-offload stores + 16 global_load_lds + counted vmcnt(32); loads in
// flight across raw s_barrier).
// ---------------------------------------------------------------------------
__global__ void __launch_bounds__(128, 1)
scan_kernel(const float4* __restrict__ gx,
            const int* __restrict__ minz,
            const int* __restrict__ chunkmin,
            const float* __restrict__ exc,
            float* __restrict__ y,
            float* __restrict__ sink,
            int n, int burst) {
    __shared__ float buf[2052];          // 2048 circular + 2 shadow + pad
    __shared__ float excl[2048];
    __shared__ __align__(16) int cminL[1024];
    __shared__ float4 ring[4 * 1024];    // 4 group-slots x 1024 float4 = 64 KB

    const int tid = threadIdx.x;
    for (int i = tid; i < 2052; i += 128) buf[i] = 0.0f;
    for (int i = tid; i < 2048; i += 128) excl[i] = (i < burst) ? exc[i] : 0.0f;
    {
        int nCh = (n + 127) >> 7;
        for (int i = tid; i < 1024; i += 128)
            cminL[i] = (i < nCh) ? chunkmin[i] : 0x7fffffff;
    }

    int mz = __builtin_amdgcn_readfirstlane(*minz);
    const int nFull = n >> 10;

#define GLL(gsrc, ldst)                                                       \
    __builtin_amdgcn_global_load_lds(                                         \
        (const __attribute__((address_space(1))) void*)(gsrc),                \
        (__attribute__((address_space(3))) void*)(ldst), 16, 0, 0)

    // ---------------- fallback (never taken for this data: mz ~ 100) -------
    if (mz < 63 || nFull < 2) {
        __syncthreads();
        if (tid < 64) {
            int Df = mz + 1;
            if (Df > 64) Df = 64;
            if (Df < 1) Df = 1;
            for (int base = 0; base < n; base += Df) {
                int t = base + tid;
                bool ok = (tid < Df) && (t < n);
                float4 q = ok ? gx[t] : make_float4(0.f, 0.f, 0.f, 0.f);
                unsigned u = __float_as_uint(q.w);
                float a3 = buf[u], a2 = buf[u + 1], a1 = buf[u + 2];
                float x = (t < burst) ? excl[t & 2047] : 0.0f;
                float y0 = fmaf(q.x, a1, x);
                y0 = fmaf(q.y, a2, y0);
                y0 = fmaf(q.z, a3, y0);
                if (ok) {
                    int w = t & 2047;
                    buf[w] = y0;
                    if (w < 2) buf[2048 + w] = y0;
                    y[t] = y0;
                }
            }
        }
        return;
    }

    // ---------------- prologue: producer fills groups 0,1 ------------------
    if (tid >= 64) {
        int lane = tid - 64;
        #pragma unroll
        for (int c = 0; c < 16; ++c)
            GLL(gx + (c << 6) + lane, &ring[(c << 6)]);
        #pragma unroll
        for (int c = 0; c < 16; ++c)
            GLL(gx + 1024 + (c << 6) + lane, &ring[1024 + (c << 6)]);
    }
    __syncthreads();   // full drain: groups 0,1 resident; buf/excl/cmin visible

    for (int g = 0; g < nFull; ++g) {
        if (tid >= 64) {
            // ---------------- producer (R13 verbatim) ----------------
            int lane = tid - 64;
            int prevw = ((g - 1) & 1) << 10;
            int prev = (g - 1) << 10;
            float vals[16];
            #pragma unroll
            for (int k = 0; k < 16; ++k)
                vals[k] = buf[prevw + (k << 6) + lane];
            #pragma unroll
            for (int k = 0; k < 16; ++k) {
                int off = (k << 6) + lane;
                float* dst = (g > 0) ? (y + prev + off) : (sink + off);
                *dst = vals[k];                    // exactly 16 stores
            }
            int pb = (g + 2) << 10;
            int slot = (g + 2) & 3;
            #pragma unroll
            for (int c = 0; c < 16; ++c)
                GLL(gx + pb + (c << 6) + lane, &ring[(slot << 10) + (c << 6)]);
            asm volatile("s_waitcnt vmcnt(32)" ::: "memory");
        } else {
            // ---------------- consumer: 8 x 128-chunks, flag branch --------
            const float4* Rp = ring + ((g & 3) << 10);
            int wb = ((g & 1) << 10) + tid;
            int gb = g << 10;
            bool wx = (gb < burst);                // uniform; first 2 groups
            int g8 = g << 3;
            int4 fa = *(const int4*)&cminL[g8];
            int4 fb = *(const int4*)&cminL[g8 + 4];
            int fl[8] = { fa.x, fa.y, fa.z, fa.w, fb.x, fb.y, fb.z, fb.w };
            float4 q0 = Rp[tid];
            float4 q1 = Rp[64 + tid];
            #pragma unroll
            for (int c = 0; c < 8; ++c) {
                float4 p0, p1;
                if (c < 7) {
                    p0 = Rp[((c + 1) << 7) + tid];
                    p1 = Rp[((c + 1) << 7) + 64 + tid];
                }
                float x0 = 0.0f, x1 = 0.0f;
                if (wx) {
                    int t = gb + (c << 7) + tid;
                    x0 = (t < burst) ? excl[t & 2047] : 0.0f;
                    int t1 = t + 64;
                    x1 = (t1 < burst) ? excl[t1 & 2047] : 0.0f;
                }
                if (__builtin_amdgcn_readfirstlane(fl[c]) >= 127) {
                    // FAST: both rows' taps < chunk base -> all reads first
                    unsigned u0 = __float_as_uint(q0.w);
                    unsigned u1 = __float_as_uint(q1.w);
                    float a3 = buf[u0], a2 = buf[u0 + 1], a1 = buf[u0 + 2];
                    float b3 = buf[u1], b2 = buf[u1 + 1], b1 = buf[u1 + 2];
                    float y0 = fmaf(q0.x, a1, x0);
                    y0 = fmaf(q0.y, a2, y0);
                    y0 = fmaf(q0.z, a3, y0);
                    float y1 = fmaf(q1.x, b1, x1);
                    y1 = fmaf(q1.y, b2, y1);
                    y1 = fmaf(q1.z, b3, y1);
                    buf[wb + (c << 7)] = y0;
                    buf[wb + (c << 7) + 64] = y1;
                    if (c == 0 && (g & 1) == 0 && tid < 2) buf[2048 + tid] = y0;
                } else {
                    // SLOW: row1 may tap row0's outputs -> sequential rows
                    unsigned u0 = __float_as_uint(q0.w);
                    float a3 = buf[u0], a2 = buf[u0 + 1], a1 = buf[u0 + 2];
                    float y0 = fmaf(q0.x, a1, x0);
                    y0 = fmaf(q0.y, a2, y0);
                    y0 = fmaf(q0.z, a3, y0);
                    buf[wb + (c << 7)] = y0;
                    if (c == 0 && (g & 1) == 0 && tid < 2) buf[2048 + tid] = y0;
                    unsigned u1 = __float_as_uint(q1.w);
                    float b3 = buf[u1], b2 = buf[u1 + 1], b1 = buf[u1 + 2];
                    float y1 = fmaf(q1.x, b1, x1);
                    y1 = fmaf(q1.y, b2, y1);
                    y1 = fmaf(q1.z, b3, y1);
                    buf[wb + (c << 7) + 64] = y1;
                }
                q0 = p0; q1 = p1;
            }
        }
        // raw barrier: producer's g+2 loads stay in flight across it
        asm volatile("s_waitcnt lgkmcnt(0)" ::: "memory");
        __builtin_amdgcn_sched_barrier(0);
        __builtin_amdgcn_s_barrier();
        __builtin_amdgcn_sched_barrier(0);
    }

    __syncthreads();   // drain everything before epilogue

    if (tid >= 64) {
        // offload group nFull-1 (final in buf)
        int lane = tid - 64;
        int start = (nFull - 1) << 10;
        #pragma unroll
        for (int k = 0; k < 16; ++k) {
            int t = start + (k << 6) + lane;
            if (t < n) y[t] = buf[t & 2047];
        }
    } else {
        // tail samples [nFull<<10, n): direct-global, masked, D=64 serial
        for (int base = nFull << 10; base < n; base += 64) {
            int t = base + tid;
            bool ok = (t < n);
            float4 q = ok ? gx[t] : make_float4(0.f, 0.f, 0.f, 0.f);
            unsigned u = __float_as_uint(q.w);
            float a3 = buf[u], a2 = buf[u + 1], a1 = buf[u + 2];
            float x = (t < burst) ? excl[t & 2047] : 0.0f;
            float y0 = fmaf(q.x, a1, x);
            y0 = fmaf(q.y, a2, y0);
            y0 = fmaf(q.z, a3, y0);
            if (ok) {
                int w = t & 2047;
                buf[w] = y0;
                if (w < 2) buf[2048 + w] = y0;
                y[t] = y0;
            }
        }
    }
#undef GLL
}

// ---------------------------------------------------------------------------
extern "C" void kernel_launch(void* const* d_in, const int* in_sizes, int n_in,
                              void* d_out, int out_size, void* d_ws, size_t ws_size,
                              hipStream_t stream) {
    const float* delay = (const float*)d_in[0];
    const float* raw   = (const float*)d_in[1];
    const float* exc   = (const float*)d_in[2];
    int nf = in_sizes[0];
    int burst = in_sizes[2];
    if (burst > 2048) burst = 2048;
    int n = out_size;
    int nTot = n + 4096;                   // pad covers producer prefetch overshoot
    int nChTot = (nTot + 127) >> 7;

    char* ws = (char*)d_ws;
    size_t coefBytes = (size_t)3 * (nf - 1) * 4 * sizeof(double);
    size_t off = (coefBytes + 255) & ~(size_t)255;
    double* coef = (double*)ws;
    int* minz = (int*)(ws + off);
    off += 256;
    int* chunkmin = (int*)(ws + off);
    off += 8192;
    float* sink = (float*)(ws + off);
    off += 4096;
    float4* gxa = (float4*)(ws + off);

    spline_setup<<<1, 256, 0, stream>>>(delay, raw, coef, minz, chunkmin, nChTot, nf);
    eval_kernel<<<(nTot + 255) / 256, 256, 0, stream>>>(coef, gxa, minz, chunkmin, n, nTot, nf);
    scan_kernel<<<1, 128, 0, stream>>>(gxa, minz, chunkmin, exc, (float*)d_out, sink, n, burst);
}

// Round 18
// 150.073 us; speedup vs baseline: 1.3381x; 1.2255x over previous
//
#include <hip/hip_runtime.h>
#include <math.h>
#include <float.h>

#define POFF 128

// ---------------------------------------------------------------------------
// Variant selection (shared by eval + scan): largest compile-time D <= mz+1.
// M (circular-buffer modulus) = 2 * group span; span = NC*D with NC=16 for
// D=64 (R13-proven config) else 8.
// ---------------------------------------------------------------------------
__device__ __forceinline__ int select_D(int mz) {
    int dmax = mz + 1;
    if (dmax >= 128) return 128;
    if (dmax >= 112) return 112;
    if (dmax >= 96)  return 96;
    if (dmax >= 80)  return 80;
    return 64;
}
__device__ __forceinline__ int m_of(int D) { return (D == 64) ? 2048 : 16 * D; }

// ---------------------------------------------------------------------------
// Phase 1: PCR spline solve (validated R15) + ANALYTIC min of the delay
// spline (exact per-interval cubic min via derivative roots) -> minz.
// Conservative: continuous min <= sample min, so D <= sample minz + 1.
// ---------------------------------------------------------------------------
__global__ void __launch_bounds__(256)
spline_setup(const float* __restrict__ delay_in,
             const float* __restrict__ raw,
             double* __restrict__ coef,
             int* __restrict__ minz,     // [0]=analytic minz, [1]=sample minz
             int nf) {
    __shared__ double xch[3 * 256];
    __shared__ double Aa[2][512], Ab[2][512], Ac[2][512];
    __shared__ double Ad0[2][512], Ad1[2][512], Ad2[2][512];
    __shared__ double dmin[256];

    const int tid = threadIdx.x;
    if (tid == 0) minz[1] = 0x7fffffff;
    dmin[tid] = DBL_MAX;

    #pragma unroll
    for (int b = 0; b < 2; ++b)
        for (int i = tid; i < 512; i += 256) {
            Aa[b][i] = 0.0; Ab[b][i] = 1.0; Ac[b][i] = 0.0;
            Ad0[b][i] = 0.0; Ad1[b][i] = 0.0; Ad2[b][i] = 0.0;
        }

    if (tid < nf) {
        double s0 = 1.0 / (1.0 + exp(-(double)raw[2 * tid + 0]));
        double s1 = 1.0 / (1.0 + exp(-(double)raw[2 * tid + 1]));
        double ss = s0 + s1;
        xch[0 * 256 + tid] = (double)delay_in[tid];
        xch[1 * 256 + tid] = s0 / ss;
        xch[2 * 256 + tid] = s1 / ss;
    }
    __syncthreads();

    if (tid < nf) {
        int i = tid;
        double hinv = (double)(nf - 1);
        Aa[0][POFF + i] = (i > 0) ? 1.0 : 0.0;
        Ac[0][POFF + i] = (i < nf - 1) ? 1.0 : 0.0;
        Ab[0][POFF + i] = (i == 0 || i == nf - 1) ? 2.0 : 4.0;
        #pragma unroll
        for (int ch = 0; ch < 3; ++ch) {
            const double* x = xch + ch * 256;
            double r = 0.0;
            if (i < nf - 1) r += 3.0 * hinv * (x[i + 1] - x[i]);
            if (i > 0)      r += 3.0 * hinv * (x[i] - x[i - 1]);
            if (ch == 0) Ad0[0][POFF + i] = r;
            else if (ch == 1) Ad1[0][POFF + i] = r;
            else Ad2[0][POFF + i] = r;
        }
    }
    __syncthreads();

    int cur = 0;
    for (int s = 1; s < nf; s <<= 1) {
        int nxt = cur ^ 1;
        int ic = POFF + tid, im = ic - s, ip = ic + s;
        double ai = Aa[cur][ic], bi = Ab[cur][ic], ci = Ac[cur][ic];
        double alpha = -ai / Ab[cur][im];
        double gamma = -ci / Ab[cur][ip];
        double na = alpha * Aa[cur][im];
        double nc = gamma * Ac[cur][ip];
        double nb = bi + alpha * Ac[cur][im] + gamma * Aa[cur][ip];
        double n0 = Ad0[cur][ic] + alpha * Ad0[cur][im] + gamma * Ad0[cur][ip];
        double n1 = Ad1[cur][ic] + alpha * Ad1[cur][im] + gamma * Ad1[cur][ip];
        double n2 = Ad2[cur][ic] + alpha * Ad2[cur][im] + gamma * Ad2[cur][ip];
        Aa[nxt][ic] = na; Ab[nxt][ic] = nb; Ac[nxt][ic] = nc;
        Ad0[nxt][ic] = n0; Ad1[nxt][ic] = n1; Ad2[nxt][ic] = n2;
        cur = nxt;
        __syncthreads();
    }

    int nint = nf - 1;
    double hinv = (double)(nf - 1);
    if (tid < nint) {
        int i = tid;
        double rbI = 1.0 / Ab[cur][POFF + i], rbI1 = 1.0 / Ab[cur][POFF + i + 1];
        #pragma unroll
        for (int ch = 0; ch < 3; ++ch) {
            double ki, ki1;
            if (ch == 0) { ki = Ad0[cur][POFF + i] * rbI; ki1 = Ad0[cur][POFF + i + 1] * rbI1; }
            else if (ch == 1) { ki = Ad1[cur][POFF + i] * rbI; ki1 = Ad1[cur][POFF + i + 1] * rbI1; }
            else { ki = Ad2[cur][POFF + i] * rbI; ki1 = Ad2[cur][POFF + i + 1] * rbI1; }
            const double* x = xch + ch * 256;
            double dx3 = 3.0 * (x[i + 1] - x[i]);
            double two_c   = (2.0 * dx3 * hinv - 4.0 * ki - 2.0 * ki1) * hinv;
            double three_d = (-2.0 * dx3 * hinv + 3.0 * (ki + ki1)) * hinv * hinv;
            double* C = coef + (size_t)(ch * nint + i) * 4;
            C[0] = x[i];
            C[1] = ki;
            C[2] = 0.5 * two_c;
            C[3] = three_d * (1.0 / 3.0);
            if (ch == 0) {
                // exact min of cubic a + b f + (two_c/2) f^2 + (three_d/3) f^3
                // on [0, h]; p'(f) = b + two_c f + three_d f^2.
                double a = x[i], b = ki;
                double C2 = 0.5 * two_c, C3 = three_d * (1.0 / 3.0);
                double h = 1.0 / hinv;
                double m = fmin(a, a + h * (b + h * (C2 + h * C3)));
                double A = three_d, B = two_c;
                if (fabs(A) > 1e-30) {
                    double disc = B * B - 4.0 * A * b;
                    if (disc >= 0.0) {
                        double sq = sqrt(disc);
                        double r1 = (-B + sq) / (2.0 * A);
                        double r2 = (-B - sq) / (2.0 * A);
                        if (r1 > 0.0 && r1 < h)
                            m = fmin(m, a + r1 * (b + r1 * (C2 + r1 * C3)));
                        if (r2 > 0.0 && r2 < h)
                            m = fmin(m, a + r2 * (b + r2 * (C2 + r2 * C3)));
                    }
                } else if (fabs(B) > 1e-30) {
                    double r = -b / B;
                    if (r > 0.0 && r < h)
                        m = fmin(m, a + r * (b + r * (C2 + r * C3)));
                }
                dmin[i] = m;
            }
        }
    }
    __syncthreads();
    #pragma unroll
    for (int s = 128; s > 0; s >>= 1) {
        if (tid < s) dmin[tid] = fmin(dmin[tid], dmin[tid + s]);
        __syncthreads();
    }
    if (tid == 0) minz[0] = (int)floor(dmin[0]);
}

// ---------------------------------------------------------------------------
// Phase 2: per-sample spline eval -> {g1, g2, g3, s3} one float4.
// s3 = (t - z - 3) mod M, M chosen from analytic minz (matches scan's
// variant). Sample min z -> minz[1] (safety check). Pads [n, nTot) zeros.
// ---------------------------------------------------------------------------
__global__ void eval_kernel(const double* __restrict__ coef,
                            float4* __restrict__ gx,
                            int* __restrict__ minz,
                            int n, int nTot, int nf) {
    int j = blockIdx.x * blockDim.x + threadIdx.x;
    if (j >= nTot) return;
    if (j >= n) { gx[j] = make_float4(0.f, 0.f, 0.f, 0.f); return; }

    int M = m_of(select_D(minz[0]));

    double u = (double)j / (double)(n - 1);
    double nfm1 = (double)(nf - 1);
    int idx = (int)(u * nfm1);
    if (idx > nf - 2) idx = nf - 2;
    if (idx < 0) idx = 0;
    double tknot = (double)idx / nfm1;
    if (u < tknot && idx > 0) {
        idx--; tknot = (double)idx / nfm1;
    } else {
        double tnext = (double)(idx + 1) / nfm1;
        if (u >= tnext && idx < nf - 2) { idx++; tknot = tnext; }
    }
    double f = u - tknot;

    int nint = nf - 1;
    const double* C0 = coef + (size_t)(0 * nint + idx) * 4;
    const double* C1 = coef + (size_t)(1 * nint + idx) * 4;
    const double* C2 = coef + (size_t)(2 * nint + idx) * 4;
    double dly = C0[0] + f * (C0[1] + f * (C0[2] + f * C0[3]));
    double b1d = C1[0] + f * (C1[1] + f * (C1[2] + f * C1[3]));
    double b2d = C2[0] + f * (C2[1] + f * (C2[2] + f * C2[3]));

    double zf = floor(dly);
    int z = (int)zf;
    float alfa = (float)(dly - zf);
    float b1 = (float)b1d, b2 = (float)b2d;
    float g1 = b1 * (1.0f - alfa);
    float g2 = b1 * alfa + b2 * (1.0f - alfa);
    float g3 = b2 * alfa;

    int s3 = (j - z - 3) % M;
    if (s3 < 0) s3 += M;
    gx[j] = make_float4(g1, g2, g3, __uint_as_float((unsigned int)s3));

    int wmin = z;
    #pragma unroll
    for (int o = 32; o > 0; o >>= 1) wmin = min(wmin, __shfl_down(wmin, o, 64));
    if ((threadIdx.x & 63) == 0) atomicMin(&minz[1], wmin);
}

// ---------------------------------------------------------------------------
// Phase 3 body, templated on compile-time D. R13's proven structure:
// producer/consumer, minimal row body, all offsets compile-time.
// NC chunks/group; span = NC*D; M = 2*span; ring 4 slots x 1024 f4.
// Producer: NP=span/64 y-offload stores + NC*ROWS=16 global_load_lds
// (group g+2) + counted vmcnt(NP+16); loads in flight across raw barrier.
// ---------------------------------------------------------------------------
#define GLLm(gsrc, ldst)                                                      \
    __builtin_amdgcn_global_load_lds(                                         \
        (const __attribute__((address_space(1))) void*)(gsrc),                \
        (__attribute__((address_space(3))) void*)(ldst), 16, 0, 0)

template<int D>
__device__ __forceinline__ void scan_body(const float4* __restrict__ gx,
                                          float* __restrict__ y,
                                          float* __restrict__ sink,
                                          int n, int burst, int tid,
                                          float (&buf)[2052], float (&excl)[2048],
                                          float4 (&ring)[4096]) {
    constexpr int NC   = (D == 64) ? 16 : 8;    // chunks per group
    constexpr int ROWS = (D == 64) ? 1 : 2;
    constexpr int CST  = (D == 64) ? 64 : 128;  // ring chunk stride (f4)
    constexpr int SPAN = NC * D;
    constexpr int M    = 2 * SPAN;
    constexpr int NP   = SPAN / 64;             // producer store rows
    const int nFull = n / SPAN;

    // prologue: producer fills ring slots 0,1 (groups 0,1)
    if (tid >= 64) {
        int lane = tid - 64;
        #pragma unroll
        for (int c = 0; c < NC; ++c) {
            GLLm(gx + c * D + lane, &ring[c * CST]);
            if constexpr (ROWS == 2) GLLm(gx + c * D + 64 + lane, &ring[c * CST + 64]);
        }
        #pragma unroll
        for (int c = 0; c < NC; ++c) {
            GLLm(gx + SPAN + c * D + lane, &ring[1024 + c * CST]);
            if constexpr (ROWS == 2) GLLm(gx + SPAN + c * D + 64 + lane, &ring[1024 + c * CST + 64]);
        }
    }
    __syncthreads();   // full drain: groups 0,1 resident

    for (int g = 0; g < nFull; ++g) {
        if (tid >= 64) {
            // ---------------- producer ----------------
            int lane = tid - 64;
            int prevw = ((g - 1) & 1) ? SPAN : 0;
            int prev = (g - 1) * SPAN;
            float vals[NP];
            #pragma unroll
            for (int k = 0; k < NP; ++k)
                vals[k] = buf[prevw + (k << 6) + lane];
            #pragma unroll
            for (int k = 0; k < NP; ++k) {
                int off = (k << 6) + lane;
                float* dst = (g > 0) ? (y + prev + off) : (sink + off);
                *dst = vals[k];                    // exactly NP stores
            }
            int pb = (g + 2) * SPAN;
            int slot = (g + 2) & 3;
            #pragma unroll
            for (int c = 0; c < NC; ++c) {
                GLLm(gx + pb + c * D + lane, &ring[(slot << 10) + c * CST]);
                if constexpr (ROWS == 2)
                    GLLm(gx + pb + c * D + 64 + lane, &ring[(slot << 10) + c * CST + 64]);
            }
            // counted wait: prev group's ops drained (incl. g+1's 16 loads)
            if constexpr (NP + 16 == 32) asm volatile("s_waitcnt vmcnt(32)" ::: "memory");
            else if constexpr (NP + 16 == 30) asm volatile("s_waitcnt vmcnt(30)" ::: "memory");
            else if constexpr (NP + 16 == 28) asm volatile("s_waitcnt vmcnt(28)" ::: "memory");
            else if constexpr (NP + 16 == 26) asm volatile("s_waitcnt vmcnt(26)" ::: "memory");
        } else {
            // ---------------- consumer (pure LDS, minimal body) ----------
            const float4* Rp = ring + ((g & 3) << 10);
            int wb = (((g & 1) ? SPAN : 0)) + tid;
            int gb = g * SPAN;
            bool wx = (gb < burst);                // uniform; first few groups
            float4 q0 = Rp[tid];
            float4 q1;
            if constexpr (ROWS == 2) q1 = Rp[64 + tid];
            #pragma unroll
            for (int c = 0; c < NC; ++c) {
                float4 p0, p1;
                if (c < NC - 1) {
                    p0 = Rp[(c + 1) * CST + tid];
                    if constexpr (ROWS == 2) p1 = Rp[(c + 1) * CST + 64 + tid];
                }
                unsigned u0 = __float_as_uint(q0.w);
                float a3 = buf[u0], a2 = buf[u0 + 1], a1 = buf[u0 + 2];
                float x0 = 0.0f, x1 = 0.0f;
                if (wx) {
                    int t = gb + c * D + tid;
                    x0 = (t < burst) ? excl[t & 2047] : 0.0f;
                    if constexpr (ROWS == 2) {
                        int t1 = t + 64;
                        x1 = (t1 < burst) ? excl[t1 & 2047] : 0.0f;
                    }
                }
                float y0 = fmaf(q0.x, a1, x0);
                y0 = fmaf(q0.y, a2, y0);
                y0 = fmaf(q0.z, a3, y0);
                buf[wb + c * D] = y0;
                if constexpr (ROWS == 2) {
                    unsigned u1 = __float_as_uint(q1.w);
                    float b3 = buf[u1], b2 = buf[u1 + 1], b1 = buf[u1 + 2];
                    float y1 = fmaf(q1.x, b1, x1);
                    y1 = fmaf(q1.y, b2, y1);
                    y1 = fmaf(q1.z, b3, y1);
                    if constexpr (D == 128) {
                        buf[wb + c * D + 64] = y1;
                    } else {
                        if (tid < D - 64) buf[wb + c * D + 64] = y1;
                    }
                }
                if (c == 0 && (g & 1) == 0 && tid < 2) buf[M + tid] = y0;
                q0 = p0;
                if constexpr (ROWS == 2) q1 = p1;
            }
        }
        // raw barrier: producer's g+2 loads stay in flight across it
        asm volatile("s_waitcnt lgkmcnt(0)" ::: "memory");
        __builtin_amdgcn_sched_barrier(0);
        __builtin_amdgcn_s_barrier();
        __builtin_amdgcn_sched_barrier(0);
    }

    __syncthreads();   // drain everything before epilogue

    if (tid >= 64) {
        // offload group nFull-1 (final in buf)
        int lane = tid - 64;
        int start = (nFull - 1) * SPAN;
        int w = ((nFull - 1) & 1) ? SPAN : 0;
        #pragma unroll
        for (int k = 0; k < NP; ++k) {
            int off = (k << 6) + lane;
            y[start + off] = buf[w + off];
        }
    } else {
        // tail samples [nFull*SPAN, n): 64-chunks, serial, masked
        int tb = nFull * SPAN;
        int wb0 = (nFull & 1) ? SPAN : 0;
        for (int base = tb; base < n; base += 64) {
            int t = base + tid;
            bool ok = (t < n);
            float4 q = ok ? gx[t] : make_float4(0.f, 0.f, 0.f, 0.f);
            unsigned u = __float_as_uint(q.w);
            float a3 = buf[u], a2 = buf[u + 1], a1 = buf[u + 2];
            float y0 = q.x * a1;     // tail is far past burst: no excitation
            y0 = fmaf(q.y, a2, y0);
            y0 = fmaf(q.z, a3, y0);
            if (ok) {
                int w = wb0 + (t - tb);
                buf[w] = y0;
                if (w < 2) buf[M + w] = y0;
                y[t] = y0;
            }
        }
    }
}

// ---------------------------------------------------------------------------
__global__ void __launch_bounds__(128, 1)
scan_kernel(const float4* __restrict__ gx,
            const int* __restrict__ minz,
            const float* __restrict__ exc,
            float* __restrict__ y,
            float* __restrict__ sink,
            int n, int burst) {
    __shared__ float buf[2052];
    __shared__ float excl[2048];
    __shared__ float4 ring[4096];      // 64 KB

    const int tid = threadIdx.x;
    for (int i = tid; i < 2052; i += 128) buf[i] = 0.0f;
    for (int i = tid; i < 2048; i += 128) excl[i] = (i < burst) ? exc[i] : 0.0f;

    int mza = __builtin_amdgcn_readfirstlane(minz[0]);   // analytic
    int smz = __builtin_amdgcn_readfirstlane(minz[1]);   // sample (check)
    int D = select_D(mza);
    int M = m_of(D);

    bool fast = (mza >= 63) && (D <= smz + 1) && (n / ((D == 64) ? 1024 : 8 * D)) >= 2;

    if (!fast) {
        // safety fallback: serial 64-chunks, runtime M window tracking
        __syncthreads();
        if (tid < 64) {
            int Df = smz + 1;
            if (Df > 64) Df = 64;
            if (Df < 1) Df = 1;
            int wb = 0;
            for (int base = 0; base < n; base += Df) {
                int t = base + tid;
                bool ok = (tid < Df) && (t < n);
                float4 q = ok ? gx[t] : make_float4(0.f, 0.f, 0.f, 0.f);
                unsigned u = __float_as_uint(q.w);
                float a3 = buf[u], a2 = buf[u + 1], a1 = buf[u + 2];
                float x = (t < burst) ? excl[t & 2047] : 0.0f;
                float y0 = fmaf(q.x, a1, x);
                y0 = fmaf(q.y, a2, y0);
                y0 = fmaf(q.z, a3, y0);
                if (ok) {
                    int w = wb + tid;
                    if (w >= M) w -= M;
                    buf[w] = y0;
                    if (w < 2) buf[M + w] = y0;
                    y[t] = y0;
                }
                wb += Df;
                if (wb >= M) wb -= M;
            }
        }
        return;
    }

    switch (D) {
        case 128: scan_body<128>(gx, y, sink, n, burst, tid, buf, excl, ring); break;
        case 112: scan_body<112>(gx, y, sink, n, burst, tid, buf, excl, ring); break;
        case 96:  scan_body<96>(gx, y, sink, n, burst, tid, buf, excl, ring); break;
        case 80:  scan_body<80 >(gx, y, sink, n, burst, tid, buf, excl, ring); break;
        default:  scan_body<64 >(gx, y, sink, n, burst, tid, buf, excl, ring); break;
    }
}

// ---------------------------------------------------------------------------
extern "C" void kernel_launch(void* const* d_in, const int* in_sizes, int n_in,
                              void* d_out, int out_size, void* d_ws, size_t ws_size,
                              hipStream_t stream) {
    const float* delay = (const float*)d_in[0];
    const float* raw   = (const float*)d_in[1];
    const float* exc   = (const float*)d_in[2];
    int nf = in_sizes[0];
    int burst = in_sizes[2];
    if (burst > 2048) burst = 2048;
    int n = out_size;
    int nTot = n + 4096;   // pad covers producer prefetch overshoot (2 spans)

    char* ws = (char*)d_ws;
    size_t coefBytes = (size_t)3 * (nf - 1) * 4 * sizeof(double);
    size_t off = (coefBytes + 255) & ~(size_t)255;
    double* coef = (double*)ws;
    int* minz = (int*)(ws + off);      // [0]=analytic, [1]=sample
    off += 256;
    float* sink = (float*)(ws + off);
    off += 4096;
    float4* gxa = (float4*)(ws + off);

    spline_setup<<<1, 256, 0, stream>>>(delay, raw, coef, minz, nf);
    eval_kernel<<<(nTot + 255) / 256, 256, 0, stream>>>(coef, gxa, minz, n, nTot, nf);
    scan_kernel<<<1, 128, 0, stream>>>(gxa, minz, exc, (float*)d_out, sink, n, burst);
}